// Round 1
// baseline (146.852 us; speedup 1.0000x reference)
//
#include <hip/hip_runtime.h>

// B=64, D=512 (ZD=E), L=8192, NL=1000, fp32 in/out. No atomics. 3 dispatches.
// out[b,l] = s[b] * dot(zz[b,:], W_zlat[l,:])
// Algebra: s_b = GH[b].u1 + by1.u1 + by2.w_proj, GH = G + G@Wy1^T,
//          G[b,:] = W_yemb[:,y_b] + b_yemb  (depends only on inputs!)
//   k1: X1 = z + z@Wz1^T + bz1 (full-K, reduced) ; u1 = w + Wy2^T w ;
//       GH GEMM with on-the-fly gather (scheduled FIRST: HBM-cold strided)
//   k2: zzs = bf16(X1 + X1@Wz2^T + bz2) UNSCALED ; s[b] finalize (tiny)
//   k3: MFMA big GEMM (proven kC), epilogue acc *= s[b]
// R9 lesson: grid-wide fusion costs ~100 µs in fence L2-writebacks -> no
// cross-block deps inside a dispatch; 3 dispatches is the dependency floor
// (z-path is L1 -> L2 -> big GEMM, inherently sequential).

#define BB 64
#define DD 512
#define LL 8192
#define NLBL 1000

typedef __attribute__((ext_vector_type(8))) short short8;
typedef __attribute__((ext_vector_type(4))) float f32x4;

__device__ __forceinline__ unsigned short f2bf(float f) {
  unsigned u = __float_as_uint(f);
  return (unsigned short)((u + 0x7fffu + ((u >> 16) & 1u)) >> 16);   // RNE
}

// ---------- matvec: vout = vin + W^T vin (one 32-wide e-chunk) ----------
__device__ __forceinline__ void matvec_block(int eblk, const float* __restrict__ W,
                                             const float* __restrict__ vin,
                                             float* __restrict__ vout) {
  __shared__ float vl[DD];
  __shared__ float red[256];
  int tid = threadIdx.x;
  vl[tid] = vin[tid];
  vl[tid + 256] = vin[tid + 256];
  __syncthreads();
  int el = tid & 31, jg = tid >> 5;
  int e = eblk * 32 + el;
  float acc = 0.f;
  for (int j = jg; j < DD; j += 8)
    acc += W[j * DD + e] * vl[j];
  red[tid] = acc;
  __syncthreads();
  if (tid < 32) {
    float s = vl[eblk * 32 + tid];
#pragma unroll
    for (int g = 0; g < 8; ++g) s += red[g * 32 + tid];
    vout[eblk * 32 + tid] = s;
  }
}

// ---------- full-K residual GEMM tile: K=512, A-tile 8 rows in LDS ----------
// out[b0+bg][j] = dot(A[b,:], W[j,:]) + A[b,j] (+ bias[j]), j = j0+jl(+32*o)
// A staged in LDS (8x512 f32 = 16 KB); W rows streamed from global (each 64B
// line used fully across the k-loop -> L1 absorbs the 2KB-stride pattern).
// 4 independent accumulators break the fmac dependence chain (grid ~1 blk/CU
// -> ILP, not TLP, hides latency); unroll 4 keeps 4 dwordx4 loads in flight.
template <int GATHER, int BF16OUT, int JW, int HASBIAS>
__device__ __forceinline__ void gemm_fullk(
    int blk, const float* __restrict__ Ain,
    const float* __restrict__ Wemb, const float* __restrict__ bemb,
    const int* __restrict__ y,
    const float* __restrict__ W, const float* __restrict__ bias,
    float* __restrict__ outf, unsigned short* __restrict__ outh) {
  __shared__ __align__(16) float As[8][DD];
  int tid = threadIdx.x;
  constexpr int NJT = DD / JW;
  int bt = blk / NJT, jt = blk % NJT;
  int b0 = bt * 8, j0 = jt * JW;
  if (GATHER) {
    // G[b,k] = W_yemb[k, y_b] + b_yemb[k]; stride-4000B gather (inherent)
#pragma unroll
    for (int r = 0; r < 8; ++r) {
      int yb = y[b0 + r];
      As[r][tid]       = Wemb[(size_t)tid * NLBL + yb]         + bemb[tid];
      As[r][tid + 256] = Wemb[(size_t)(tid + 256) * NLBL + yb] + bemb[tid + 256];
    }
  } else {
#pragma unroll
    for (int i = 0; i < 4; ++i) {
      int g = tid + i * 256;                  // 1024 float4 granules
      int row = g >> 7, c4 = (g & 127) << 2;
      *(float4*)&As[row][c4] = *(const float4*)&Ain[(size_t)(b0 + row) * DD + c4];
    }
  }
  __syncthreads();
  int jl = tid & 31, bg = tid >> 5;
  constexpr int NO = JW / 32;
  const float* wr[NO];
#pragma unroll
  for (int o = 0; o < NO; ++o) wr[o] = W + (size_t)(j0 + o * 32 + jl) * DD;
  float a0[NO] = {}, a1[NO] = {}, a2[NO] = {}, a3[NO] = {};
#pragma unroll 4
  for (int k4 = 0; k4 < 128; ++k4) {
    float4 av = *(const float4*)&As[bg][k4 << 2];   // 2 addrs/wave: broadcast
#pragma unroll
    for (int o = 0; o < NO; ++o) {
      float4 wv = *(const float4*)&wr[o][k4 << 2];
      a0[o] = fmaf(av.x, wv.x, a0[o]);
      a1[o] = fmaf(av.y, wv.y, a1[o]);
      a2[o] = fmaf(av.z, wv.z, a2[o]);
      a3[o] = fmaf(av.w, wv.w, a3[o]);
    }
  }
#pragma unroll
  for (int o = 0; o < NO; ++o) {
    int j = j0 + o * 32 + jl;
    float v = (a0[o] + a1[o]) + (a2[o] + a3[o]) + As[bg][j];
    if (HASBIAS) v += bias[j];
    if (BF16OUT) outh[(size_t)(b0 + bg) * DD + j] = f2bf(v);
    else         outf[(size_t)(b0 + bg) * DD + j] = v;
  }
}

// ---------- s finalize: s[b] = GH[b].u1 + by1.u1 + by2.w_proj ----------
__device__ __forceinline__ void s_block(int cid, const float* __restrict__ GH,
                                        const float* __restrict__ u1,
                                        const float* __restrict__ by1,
                                        const float* __restrict__ by2,
                                        const float* __restrict__ w_proj,
                                        float* __restrict__ sv) {
  __shared__ float red[256];
  __shared__ float d2s;
  int tid = threadIdx.x;
  float p = by1[tid] * u1[tid] + by2[tid] * w_proj[tid] +
            by1[tid + 256] * u1[tid + 256] + by2[tid + 256] * w_proj[tid + 256];
  red[tid] = p;
  __syncthreads();
  if (tid < 64) {
    float s = red[tid] + red[tid + 64] + red[tid + 128] + red[tid + 192];
#pragma unroll
    for (int d = 32; d; d >>= 1) s += __shfl_down(s, d, 64);
    if (tid == 0) d2s = s;
  }
  __syncthreads();
  int bloc = tid >> 6, lane = tid & 63;
  int b = cid * 4 + bloc;
  int e0 = lane * 8;
  float4 g0 = *(const float4*)&GH[(size_t)b * DD + e0];
  float4 g1 = *(const float4*)&GH[(size_t)b * DD + e0 + 4];
  float4 ua = *(const float4*)&u1[e0];
  float4 ub = *(const float4*)&u1[e0 + 4];
  float sg = g0.x * ua.x + g0.y * ua.y + g0.z * ua.z + g0.w * ua.w +
             g1.x * ub.x + g1.y * ub.y + g1.z * ub.z + g1.w * ub.w;
#pragma unroll
  for (int d = 32; d; d >>= 1) sg += __shfl_down(sg, d, 64);
  if (lane == 0) sv[b] = sg + d2s;
}

// ---------------- k1: GH GEMM (gather) + layer1 + u1 matvec ----------------
// GH blocks FIRST (blk 0..63): they carry the HBM-cold strided W_yemb gather,
// so they get CUs earliest. 208 blocks total -> single wave-of-blocks.
__global__ __launch_bounds__(256) void k1(
    const float* __restrict__ z, const float* __restrict__ Wz1,
    const float* __restrict__ bz1, float* __restrict__ X1,
    const float* __restrict__ Wy2, const float* __restrict__ w_proj,
    float* __restrict__ u1, const float* __restrict__ W_yemb,
    const float* __restrict__ b_yemb, const int* __restrict__ y,
    const float* __restrict__ Wy1, float* __restrict__ GH) {
  int blk = blockIdx.x;
  if (blk < 64)
    gemm_fullk<1, 0, 64, 0>(blk, nullptr, W_yemb, b_yemb, y, Wy1, nullptr, GH, nullptr);
  else if (blk < 192)
    gemm_fullk<0, 0, 32, 1>(blk - 64, z, nullptr, nullptr, nullptr, Wz1, bz1, X1, nullptr);
  else
    matvec_block(blk - 192, Wy2, w_proj, u1);
}

// ---------------- k2: layer2 -> zzs (bf16, unscaled) + s finalize ----------
__global__ __launch_bounds__(256) void k2(
    const float* __restrict__ X1, const float* __restrict__ Wz2,
    const float* __restrict__ bz2, unsigned short* __restrict__ zzs,
    const float* __restrict__ GH, const float* __restrict__ u1,
    const float* __restrict__ by1, const float* __restrict__ by2,
    const float* __restrict__ w_proj, float* __restrict__ sv) {
  int blk = blockIdx.x;
  if (blk < 128)
    gemm_fullk<0, 1, 32, 1>(blk, X1, nullptr, nullptr, nullptr, Wz2, bz2, nullptr, zzs);
  else
    s_block(blk - 128, GH, u1, by1, by2, w_proj, sv);
}

// ---------------- kC: out[b,l] = s[b] * dot(zzs[b,:], W[l,:]) ---------------
// 512 blocks, l-tile 16 (l0 = blk*16), full K=512. Proven R9 structure; only
// change: zzs is UNSCALED, s[b] applied in epilogue (fp32, same rounding).
// LDS: Bs 16x512 bf16 = 16 KB -> >=2 blocks/CU. XOR-granule swizzle
// phys = c ^ (row & 7) (16-B granules). A-fragments straight from zzs global.
__global__ __launch_bounds__(256) void kC(const unsigned short* __restrict__ zzs,
                                          const float* __restrict__ W,
                                          const float* __restrict__ sv,
                                          float* __restrict__ out) {
  __shared__ __align__(16) unsigned short Bs[16 * 512];
  __shared__ float ss[64];
  int tid = threadIdx.x;
  int l0 = blockIdx.x * 16;
  if (tid < 64) ss[tid] = sv[tid];
#pragma unroll
  for (int i = 0; i < 4; ++i) {      // 1024 8-float granules of W
    int gi = tid + i * 256, row = gi >> 6, c = gi & 63;
    const float* src = &W[(size_t)(l0 + row) * DD + c * 8];
    float4 v0 = *(const float4*)src;
    float4 v1 = *(const float4*)(src + 4);
    short8 h = {(short)f2bf(v0.x), (short)f2bf(v0.y), (short)f2bf(v0.z),
                (short)f2bf(v0.w), (short)f2bf(v1.x), (short)f2bf(v1.y),
                (short)f2bf(v1.z), (short)f2bf(v1.w)};
    *(short8*)&Bs[row * DD + ((c ^ (row & 7)) << 3)] = h;
  }
  __syncthreads();
  int wave = tid >> 6, lane = tid & 63, quad = lane >> 4, l15 = lane & 15;
  const unsigned short* arow = zzs + (wave * 16 + l15) * DD + quad * 8;
  f32x4 acc = {};
  short8 apf[4];
#pragma unroll
  for (int p = 0; p < 4; ++p) apf[p] = *(const short8*)(arow + p * 32);
#pragma unroll
  for (int kc = 0; kc < 4; ++kc) {
    short8 cur[4] = {apf[0], apf[1], apf[2], apf[3]};
    if (kc < 3) {
#pragma unroll
      for (int p = 0; p < 4; ++p)
        apf[p] = *(const short8*)(arow + (kc + 1) * 128 + p * 32);
    }
#pragma unroll
    for (int s = 0; s < 4; ++s) {
      int c = kc * 16 + s * 4 + quad;            // k-granule column 0..63
      short8 bf = *(const short8*)&Bs[l15 * DD + ((c ^ (l15 & 7)) << 3)];
      acc = __builtin_amdgcn_mfma_f32_16x16x32_bf16(cur[s], bf, acc, 0, 0, 0);
    }
  }
#pragma unroll
  for (int reg = 0; reg < 4; ++reg) {            // b = wave*16 + quad*4 + reg
    int b = wave * 16 + quad * 4 + reg;
    out[(size_t)b * LL + l0 + l15] = acc[reg] * ss[b];
  }
}

extern "C" void kernel_launch(void* const* d_in, const int* in_sizes, int n_in,
                              void* d_out, int out_size, void* d_ws, size_t ws_size,
                              hipStream_t stream) {
  const float* z      = (const float*)d_in[0];
  const int*   y      = (const int*)  d_in[1];
  const float* W_yemb = (const float*)d_in[2];
  const float* b_yemb = (const float*)d_in[3];
  const float* Wy1    = (const float*)d_in[4];
  const float* by1    = (const float*)d_in[5];
  const float* Wy2    = (const float*)d_in[6];
  const float* by2    = (const float*)d_in[7];
  const float* Wz1    = (const float*)d_in[8];
  const float* bz1    = (const float*)d_in[9];
  const float* Wz2    = (const float*)d_in[10];
  const float* bz2    = (const float*)d_in[11];
  const float* W_zlat = (const float*)d_in[12];
  const float* w_proj = (const float*)d_in[13];

  float* ws = (float*)d_ws;
  float* X1 = ws;                                  // floats [0     .. 32768)
  float* GH = ws + 32768;                          // floats [32768 .. 65536)
  float* u1 = ws + 65536;                          // [512]
  float* sv = ws + 66048;                          // [64]
  unsigned short* zzs = (unsigned short*)(ws + 66112);   // 32768 shorts (16B-aligned)
  float* out = (float*)d_out;

  k1<<<208, 256, 0, stream>>>(z, Wz1, bz1, X1, Wy2, w_proj, u1, W_yemb, b_yemb, y, Wy1, GH);
  k2<<<144, 256, 0, stream>>>(X1, Wz2, bz2, zzs, GH, u1, by1, by2, w_proj, sv);
  kC<<<512, 256, 0, stream>>>(zzs, W_zlat, sv, out);
}

// Round 2
// 125.445 us; speedup vs baseline: 1.1707x; 1.1707x over previous
//
#include <hip/hip_runtime.h>

// B=64, D=512 (ZD=E), L=8192, NL=1000, fp32 in/out. No atomics. 3 dispatches.
// out[b,l] = s[b] * dot(zz[b,:], W_zlat[l,:])
// Algebra: s_b = GH[b].u1 + by1.u1 + by2.w_proj, GH = G + G@Wy1^T,
//          G[b,:] = W_yemb[:,y_b] + b_yemb  (depends only on inputs!)
//   k1: X1 = z + z@Wz1^T + bz1 ; u1 = w + Wy2^T w ; GH (gather GEMM)
//   k2: zzs = bf16(X1 + X1@Wz2^T + bz2) UNSCALED ; s[b] finalize (tiny)
//   kC: MFMA big GEMM (proven), epilogue acc *= s[b]
// R1 lesson: full-K GEMM reading W rows straight from global is UNCOALESCED
// (32 lines per wave issue, 1 blk/CU -> no TLP to hide) — cost ~4 µs/layer.
// R2: full-K stays, but W is staged per 64-k chunk into LDS (coalesced
// float4, pad-68 rows = R0's proven split-K access pattern), double-buffered
// so the next chunk's HBM stage overlaps this chunk's LDS/FMA compute.
// R9 lesson: grid-wide fusion costs ~100 µs in fence L2-writebacks -> no
// cross-block deps inside a dispatch; 3 dispatches is the dependency floor.

#define BB 64
#define DD 512
#define LL 8192
#define NLBL 1000

typedef __attribute__((ext_vector_type(8))) short short8;
typedef __attribute__((ext_vector_type(4))) float f32x4;

__device__ __forceinline__ unsigned short f2bf(float f) {
  unsigned u = __float_as_uint(f);
  return (unsigned short)((u + 0x7fffu + ((u >> 16) & 1u)) >> 16);   // RNE
}

// ---------- matvec: vout = vin + W^T vin (one 32-wide e-chunk) ----------
__device__ __forceinline__ void matvec_block(int eblk, const float* __restrict__ W,
                                             const float* __restrict__ vin,
                                             float* __restrict__ vout) {
  __shared__ float vl[DD];
  __shared__ float red[256];
  int tid = threadIdx.x;
  vl[tid] = vin[tid];
  vl[tid + 256] = vin[tid + 256];
  __syncthreads();
  int el = tid & 31, jg = tid >> 5;
  int e = eblk * 32 + el;
  float acc = 0.f;
  for (int j = jg; j < DD; j += 8)
    acc += W[j * DD + e] * vl[j];
  red[tid] = acc;
  __syncthreads();
  if (tid < 32) {
    float s = vl[eblk * 32 + tid];
#pragma unroll
    for (int g = 0; g < 8; ++g) s += red[g * 32 + tid];
    vout[eblk * 32 + tid] = s;
  }
}

// ---------- full-K residual GEMM tile: 8b x JWj x K512, chunked LDS W ------
// out[b0+bg][j] = dot(A[b,:], W[j,:]) + A[b,j] (+ bias[j])
// A (8x512 fp32, 16 KB) staged once, coalesced (or gathered for GATHER=1).
// W staged per 64-k chunk into Ws[2][JW][68] (pad-68 -> 4-way b128 conflict,
// R0-proven), double-buffered: chunk c+1's global loads issue before chunk
// c's compute, barrier at loop end separates reuse of the buffer.
template <int GATHER, int BF16OUT, int JW, int HASBIAS>
__device__ __forceinline__ void gemm_fullk2(
    int blk, const float* __restrict__ Ain,
    const float* __restrict__ Wemb, const float* __restrict__ bemb,
    const int* __restrict__ y,
    const float* __restrict__ W, const float* __restrict__ bias,
    float* __restrict__ outf, unsigned short* __restrict__ outh) {
  constexpr int NO = JW / 32;
  constexpr int NJT = DD / JW;
  __shared__ __align__(16) float As[8][DD];
  __shared__ __align__(16) float Ws[2][JW][68];
  int tid = threadIdx.x;
  int bt = blk / NJT, jt = blk % NJT;
  int b0 = bt * 8, j0 = jt * JW;

  // ---- stage A (8 x 512 fp32) ----
  if (GATHER) {
    // G[b,k] = W_yemb[k, y_b] + b_yemb[k]; stride-4000B gather (inherent)
#pragma unroll
    for (int r = 0; r < 8; ++r) {
      int yb = y[b0 + r];
      As[r][tid]       = Wemb[(size_t)tid * NLBL + yb]         + bemb[tid];
      As[r][tid + 256] = Wemb[(size_t)(tid + 256) * NLBL + yb] + bemb[tid + 256];
    }
  } else {
#pragma unroll
    for (int i = 0; i < 4; ++i) {
      int g = tid + i * 256;                  // 1024 float4 granules
      int row = g >> 7, c4 = (g & 127) << 2;
      *(float4*)&As[row][c4] = *(const float4*)&Ain[(size_t)(b0 + row) * DD + c4];
    }
  }
  // ---- stage W chunk 0 (coalesced: 16 lanes x 64B contiguous per row) ----
#pragma unroll
  for (int i = 0; i < NO * 2; ++i) {
    int gi = tid + i * 256;                   // JW*16 float4 granules
    int row = gi >> 4, c4 = (gi & 15) << 2;
    *(float4*)&Ws[0][row][c4] = *(const float4*)&W[(size_t)(j0 + row) * DD + c4];
  }
  __syncthreads();

  int jl = tid & 31, bg = tid >> 5;
  float a0[NO] = {}, a1[NO] = {}, a2[NO] = {}, a3[NO] = {};
  for (int c = 0; c < 8; ++c) {
    if (c < 7) {                              // prefetch chunk c+1 into buf^1
#pragma unroll
      for (int i = 0; i < NO * 2; ++i) {
        int gi = tid + i * 256;
        int row = gi >> 4, c4 = (gi & 15) << 2;
        *(float4*)&Ws[(c + 1) & 1][row][c4] =
            *(const float4*)&W[(size_t)(j0 + row) * DD + (c + 1) * 64 + c4];
      }
    }
#pragma unroll
    for (int k4 = 0; k4 < 16; ++k4) {
      float4 av = *(const float4*)&As[bg][c * 64 + (k4 << 2)];  // broadcast
#pragma unroll
      for (int o = 0; o < NO; ++o) {
        float4 wv = *(const float4*)&Ws[c & 1][jl + o * 32][k4 << 2];
        a0[o] = fmaf(av.x, wv.x, a0[o]);
        a1[o] = fmaf(av.y, wv.y, a1[o]);
        a2[o] = fmaf(av.z, wv.z, a2[o]);
        a3[o] = fmaf(av.w, wv.w, a3[o]);
      }
    }
    __syncthreads();                          // buf^1 ready; buf reusable
  }
#pragma unroll
  for (int o = 0; o < NO; ++o) {
    int j = j0 + o * 32 + jl;
    float v = (a0[o] + a1[o]) + (a2[o] + a3[o]) + As[bg][j];
    if (HASBIAS) v += bias[j];
    if (BF16OUT) outh[(size_t)(b0 + bg) * DD + j] = f2bf(v);
    else         outf[(size_t)(b0 + bg) * DD + j] = v;
  }
}

// ---------- s finalize: s[b] = GH[b].u1 + by1.u1 + by2.w_proj ----------
__device__ __forceinline__ void s_block(int cid, const float* __restrict__ GH,
                                        const float* __restrict__ u1,
                                        const float* __restrict__ by1,
                                        const float* __restrict__ by2,
                                        const float* __restrict__ w_proj,
                                        float* __restrict__ sv) {
  __shared__ float red[256];
  __shared__ float d2s;
  int tid = threadIdx.x;
  float p = by1[tid] * u1[tid] + by2[tid] * w_proj[tid] +
            by1[tid + 256] * u1[tid + 256] + by2[tid + 256] * w_proj[tid + 256];
  red[tid] = p;
  __syncthreads();
  if (tid < 64) {
    float s = red[tid] + red[tid + 64] + red[tid + 128] + red[tid + 192];
#pragma unroll
    for (int d = 32; d; d >>= 1) s += __shfl_down(s, d, 64);
    if (tid == 0) d2s = s;
  }
  __syncthreads();
  int bloc = tid >> 6, lane = tid & 63;
  int b = cid * 4 + bloc;
  int e0 = lane * 8;
  float4 g0 = *(const float4*)&GH[(size_t)b * DD + e0];
  float4 g1 = *(const float4*)&GH[(size_t)b * DD + e0 + 4];
  float4 ua = *(const float4*)&u1[e0];
  float4 ub = *(const float4*)&u1[e0 + 4];
  float sg = g0.x * ua.x + g0.y * ua.y + g0.z * ua.z + g0.w * ua.w +
             g1.x * ub.x + g1.y * ub.y + g1.z * ub.z + g1.w * ub.w;
#pragma unroll
  for (int d = 32; d; d >>= 1) sg += __shfl_down(sg, d, 64);
  if (lane == 0) sv[b] = sg + d2s;
}

// ---------------- k1: GH GEMM (gather) + layer1 + u1 matvec ----------------
// GH blocks FIRST (blk 0..63): they carry the HBM-cold strided W_yemb gather,
// so they get CUs earliest. 208 blocks total -> ~1 block/CU.
__global__ __launch_bounds__(256) void k1(
    const float* __restrict__ z, const float* __restrict__ Wz1,
    const float* __restrict__ bz1, float* __restrict__ X1,
    const float* __restrict__ Wy2, const float* __restrict__ w_proj,
    float* __restrict__ u1, const float* __restrict__ W_yemb,
    const float* __restrict__ b_yemb, const int* __restrict__ y,
    const float* __restrict__ Wy1, float* __restrict__ GH) {
  int blk = blockIdx.x;
  if (blk < 64)
    gemm_fullk2<1, 0, 64, 0>(blk, nullptr, W_yemb, b_yemb, y, Wy1, nullptr, GH, nullptr);
  else if (blk < 192)
    gemm_fullk2<0, 0, 32, 1>(blk - 64, z, nullptr, nullptr, nullptr, Wz1, bz1, X1, nullptr);
  else
    matvec_block(blk - 192, Wy2, w_proj, u1);
}

// ---------------- k2: layer2 -> zzs (bf16, unscaled) + s finalize ----------
__global__ __launch_bounds__(256) void k2(
    const float* __restrict__ X1, const float* __restrict__ Wz2,
    const float* __restrict__ bz2, unsigned short* __restrict__ zzs,
    const float* __restrict__ GH, const float* __restrict__ u1,
    const float* __restrict__ by1, const float* __restrict__ by2,
    const float* __restrict__ w_proj, float* __restrict__ sv) {
  int blk = blockIdx.x;
  if (blk < 128)
    gemm_fullk2<0, 1, 32, 1>(blk, X1, nullptr, nullptr, nullptr, Wz2, bz2, nullptr, zzs);
  else
    s_block(blk - 128, GH, u1, by1, by2, w_proj, sv);
}

// ---------------- kC: out[b,l] = s[b] * dot(zzs[b,:], W[l,:]) ---------------
// 512 blocks, l-tile 16 (l0 = blk*16), full K=512. Proven structure; zzs is
// UNSCALED, s[b] applied in epilogue (fp32, same rounding as R0).
// LDS: Bs 16x512 bf16 = 16 KB -> >=2 blocks/CU. XOR-granule swizzle
// phys = c ^ (row & 7) (16-B granules). A-fragments straight from zzs global.
__global__ __launch_bounds__(256) void kC(const unsigned short* __restrict__ zzs,
                                          const float* __restrict__ W,
                                          const float* __restrict__ sv,
                                          float* __restrict__ out) {
  __shared__ __align__(16) unsigned short Bs[16 * 512];
  __shared__ float ss[64];
  int tid = threadIdx.x;
  int l0 = blockIdx.x * 16;
  if (tid < 64) ss[tid] = sv[tid];
#pragma unroll
  for (int i = 0; i < 4; ++i) {      // 1024 8-float granules of W
    int gi = tid + i * 256, row = gi >> 6, c = gi & 63;
    const float* src = &W[(size_t)(l0 + row) * DD + c * 8];
    float4 v0 = *(const float4*)src;
    float4 v1 = *(const float4*)(src + 4);
    short8 h = {(short)f2bf(v0.x), (short)f2bf(v0.y), (short)f2bf(v0.z),
                (short)f2bf(v0.w), (short)f2bf(v1.x), (short)f2bf(v1.y),
                (short)f2bf(v1.z), (short)f2bf(v1.w)};
    *(short8*)&Bs[row * DD + ((c ^ (row & 7)) << 3)] = h;
  }
  __syncthreads();
  int wave = tid >> 6, lane = tid & 63, quad = lane >> 4, l15 = lane & 15;
  const unsigned short* arow = zzs + (wave * 16 + l15) * DD + quad * 8;
  f32x4 acc = {};
  short8 apf[4];
#pragma unroll
  for (int p = 0; p < 4; ++p) apf[p] = *(const short8*)(arow + p * 32);
#pragma unroll
  for (int kc = 0; kc < 4; ++kc) {
    short8 cur[4] = {apf[0], apf[1], apf[2], apf[3]};
    if (kc < 3) {
#pragma unroll
      for (int p = 0; p < 4; ++p)
        apf[p] = *(const short8*)(arow + (kc + 1) * 128 + p * 32);
    }
#pragma unroll
    for (int s = 0; s < 4; ++s) {
      int c = kc * 16 + s * 4 + quad;            // k-granule column 0..63
      short8 bf = *(const short8*)&Bs[l15 * DD + ((c ^ (l15 & 7)) << 3)];
      acc = __builtin_amdgcn_mfma_f32_16x16x32_bf16(cur[s], bf, acc, 0, 0, 0);
    }
  }
#pragma unroll
  for (int reg = 0; reg < 4; ++reg) {            // b = wave*16 + quad*4 + reg
    int b = wave * 16 + quad * 4 + reg;
    out[(size_t)b * LL + l0 + l15] = acc[reg] * ss[b];
  }
}

extern "C" void kernel_launch(void* const* d_in, const int* in_sizes, int n_in,
                              void* d_out, int out_size, void* d_ws, size_t ws_size,
                              hipStream_t stream) {
  const float* z      = (const float*)d_in[0];
  const int*   y      = (const int*)  d_in[1];
  const float* W_yemb = (const float*)d_in[2];
  const float* b_yemb = (const float*)d_in[3];
  const float* Wy1    = (const float*)d_in[4];
  const float* by1    = (const float*)d_in[5];
  const float* Wy2    = (const float*)d_in[6];
  const float* by2    = (const float*)d_in[7];
  const float* Wz1    = (const float*)d_in[8];
  const float* bz1    = (const float*)d_in[9];
  const float* Wz2    = (const float*)d_in[10];
  const float* bz2    = (const float*)d_in[11];
  const float* W_zlat = (const float*)d_in[12];
  const float* w_proj = (const float*)d_in[13];

  float* ws = (float*)d_ws;
  float* X1 = ws;                                  // floats [0     .. 32768)
  float* GH = ws + 32768;                          // floats [32768 .. 65536)
  float* u1 = ws + 65536;                          // [512]
  float* sv = ws + 66048;                          // [64]
  unsigned short* zzs = (unsigned short*)(ws + 66112);   // 32768 shorts (16B-aligned)
  float* out = (float*)d_out;

  k1<<<208, 256, 0, stream>>>(z, Wz1, bz1, X1, Wy2, w_proj, u1, W_yemb, b_yemb, y, Wy1, GH);
  k2<<<144, 256, 0, stream>>>(X1, Wz2, bz2, zzs, GH, u1, by1, by2, w_proj, sv);
  kC<<<512, 256, 0, stream>>>(zzs, W_zlat, sv, out);
}

// Round 3
// 124.618 us; speedup vs baseline: 1.1784x; 1.0066x over previous
//
#include <hip/hip_runtime.h>

// B=64, D=512 (ZD=E), L=8192, NL=1000, fp32 in/out. No atomics. 3 dispatches.
// out[b,l] = s[b] * dot(zz[b,:], W_zlat[l,:])
// Algebra: s_b = GH[b].u1 + by1.u1 + by2.w_proj, GH = G + G@Wy1^T,
//          G[b,:] = W_yemb[:,y_b] + b_yemb  (depends only on inputs!)
//   k1: X1 = z + z@Wz1^T + bz1 ; u1 = w + Wy2^T w ; GH (gather GEMM)
//   k2: zzs = bf16(X1 + X1@Wz2^T + bz2) UNSCALED ; s[b] finalize (tiny)
//   kC: MFMA big GEMM, epilogue acc *= s[b]
// R1 lesson: W rows straight from global are UNCOALESCED (32 lines/issue) —
//   chunked double-buffered LDS staging (R2) fixed it: 147 -> 125.4 µs.
// R3: GH blocks move JW=64->32 (NO=1: 2 b128 + 4 fmaf per k4, halves the
//   LDS-issue-bound inner loop; gather dup x2 is L2-resident, hidden).
//   kC l-tile 16->32: 256 blocks = exactly 1/CU, single scheduling round;
//   A-fragments reused across both l-halves.
// Pad-68 for Ws is already the structural 4-way floor for b128 x 32 rows —
//   XOR swizzle gains nothing here (checked).
// R9 lesson: grid-wide fusion costs ~100 µs in fence L2-writebacks -> no
//   cross-block deps inside a dispatch; 3 dispatches is the dependency floor.

#define BB 64
#define DD 512
#define LL 8192
#define NLBL 1000

typedef __attribute__((ext_vector_type(8))) short short8;
typedef __attribute__((ext_vector_type(4))) float f32x4;

__device__ __forceinline__ unsigned short f2bf(float f) {
  unsigned u = __float_as_uint(f);
  return (unsigned short)((u + 0x7fffu + ((u >> 16) & 1u)) >> 16);   // RNE
}

// ---------- matvec: vout = vin + W^T vin (one 32-wide e-chunk) ----------
__device__ __forceinline__ void matvec_block(int eblk, const float* __restrict__ W,
                                             const float* __restrict__ vin,
                                             float* __restrict__ vout) {
  __shared__ float vl[DD];
  __shared__ float red[256];
  int tid = threadIdx.x;
  vl[tid] = vin[tid];
  vl[tid + 256] = vin[tid + 256];
  __syncthreads();
  int el = tid & 31, jg = tid >> 5;
  int e = eblk * 32 + el;
  float acc = 0.f;
  for (int j = jg; j < DD; j += 8)
    acc += W[j * DD + e] * vl[j];
  red[tid] = acc;
  __syncthreads();
  if (tid < 32) {
    float s = vl[eblk * 32 + tid];
#pragma unroll
    for (int g = 0; g < 8; ++g) s += red[g * 32 + tid];
    vout[eblk * 32 + tid] = s;
  }
}

// ---------- full-K residual GEMM tile: 8b x JWj x K512, chunked LDS W ------
// out[b0+bg][j] = dot(A[b,:], W[j,:]) + A[b,j] (+ bias[j])
// A (8x512 fp32, 16 KB) staged once, coalesced (or gathered for GATHER=1).
// W staged per 64-k chunk into Ws[2][JW][68] (pad-68 = structural-floor
// 4-way b128 conflict), double-buffered: chunk c+1's global loads issue
// before chunk c's compute; barrier at loop end separates buffer reuse.
template <int GATHER, int BF16OUT, int JW, int HASBIAS>
__device__ __forceinline__ void gemm_fullk2(
    int blk, const float* __restrict__ Ain,
    const float* __restrict__ Wemb, const float* __restrict__ bemb,
    const int* __restrict__ y,
    const float* __restrict__ W, const float* __restrict__ bias,
    float* __restrict__ outf, unsigned short* __restrict__ outh) {
  constexpr int NO = JW / 32;
  constexpr int NJT = DD / JW;
  __shared__ __align__(16) float As[8][DD];
  __shared__ __align__(16) float Ws[2][JW][68];
  int tid = threadIdx.x;
  int bt = blk / NJT, jt = blk % NJT;
  int b0 = bt * 8, j0 = jt * JW;

  // ---- stage A (8 x 512 fp32) ----
  if (GATHER) {
    // G[b,k] = W_yemb[k, y_b] + b_yemb[k]; stride-4000B gather (inherent)
#pragma unroll
    for (int r = 0; r < 8; ++r) {
      int yb = y[b0 + r];
      As[r][tid]       = Wemb[(size_t)tid * NLBL + yb]         + bemb[tid];
      As[r][tid + 256] = Wemb[(size_t)(tid + 256) * NLBL + yb] + bemb[tid + 256];
    }
  } else {
#pragma unroll
    for (int i = 0; i < 4; ++i) {
      int g = tid + i * 256;                  // 1024 float4 granules
      int row = g >> 7, c4 = (g & 127) << 2;
      *(float4*)&As[row][c4] = *(const float4*)&Ain[(size_t)(b0 + row) * DD + c4];
    }
  }
  // ---- stage W chunk 0 (coalesced: 16 lanes x 64B contiguous per row) ----
#pragma unroll
  for (int i = 0; i < NO * 2; ++i) {
    int gi = tid + i * 256;                   // JW*16 float4 granules
    int row = gi >> 4, c4 = (gi & 15) << 2;
    *(float4*)&Ws[0][row][c4] = *(const float4*)&W[(size_t)(j0 + row) * DD + c4];
  }
  __syncthreads();

  int jl = tid & 31, bg = tid >> 5;
  float a0[NO] = {}, a1[NO] = {}, a2[NO] = {}, a3[NO] = {};
  for (int c = 0; c < 8; ++c) {
    if (c < 7) {                              // prefetch chunk c+1 into buf^1
#pragma unroll
      for (int i = 0; i < NO * 2; ++i) {
        int gi = tid + i * 256;
        int row = gi >> 4, c4 = (gi & 15) << 2;
        *(float4*)&Ws[(c + 1) & 1][row][c4] =
            *(const float4*)&W[(size_t)(j0 + row) * DD + (c + 1) * 64 + c4];
      }
    }
#pragma unroll
    for (int k4 = 0; k4 < 16; ++k4) {
      float4 av = *(const float4*)&As[bg][c * 64 + (k4 << 2)];  // broadcast
#pragma unroll
      for (int o = 0; o < NO; ++o) {
        float4 wv = *(const float4*)&Ws[c & 1][jl + o * 32][k4 << 2];
        a0[o] = fmaf(av.x, wv.x, a0[o]);
        a1[o] = fmaf(av.y, wv.y, a1[o]);
        a2[o] = fmaf(av.z, wv.z, a2[o]);
        a3[o] = fmaf(av.w, wv.w, a3[o]);
      }
    }
    __syncthreads();                          // buf^1 ready; buf reusable
  }
#pragma unroll
  for (int o = 0; o < NO; ++o) {
    int j = j0 + o * 32 + jl;
    float v = (a0[o] + a1[o]) + (a2[o] + a3[o]) + As[bg][j];
    if (HASBIAS) v += bias[j];
    if (BF16OUT) outh[(size_t)(b0 + bg) * DD + j] = f2bf(v);
    else         outf[(size_t)(b0 + bg) * DD + j] = v;
  }
}

// ---------- s finalize: s[b] = GH[b].u1 + by1.u1 + by2.w_proj ----------
__device__ __forceinline__ void s_block(int cid, const float* __restrict__ GH,
                                        const float* __restrict__ u1,
                                        const float* __restrict__ by1,
                                        const float* __restrict__ by2,
                                        const float* __restrict__ w_proj,
                                        float* __restrict__ sv) {
  __shared__ float red[256];
  __shared__ float d2s;
  int tid = threadIdx.x;
  float p = by1[tid] * u1[tid] + by2[tid] * w_proj[tid] +
            by1[tid + 256] * u1[tid + 256] + by2[tid + 256] * w_proj[tid + 256];
  red[tid] = p;
  __syncthreads();
  if (tid < 64) {
    float s = red[tid] + red[tid + 64] + red[tid + 128] + red[tid + 192];
#pragma unroll
    for (int d = 32; d; d >>= 1) s += __shfl_down(s, d, 64);
    if (tid == 0) d2s = s;
  }
  __syncthreads();
  int bloc = tid >> 6, lane = tid & 63;
  int b = cid * 4 + bloc;
  int e0 = lane * 8;
  float4 g0 = *(const float4*)&GH[(size_t)b * DD + e0];
  float4 g1 = *(const float4*)&GH[(size_t)b * DD + e0 + 4];
  float4 ua = *(const float4*)&u1[e0];
  float4 ub = *(const float4*)&u1[e0 + 4];
  float sg = g0.x * ua.x + g0.y * ua.y + g0.z * ua.z + g0.w * ua.w +
             g1.x * ub.x + g1.y * ub.y + g1.z * ub.z + g1.w * ub.w;
#pragma unroll
  for (int d = 32; d; d >>= 1) sg += __shfl_down(sg, d, 64);
  if (lane == 0) sv[b] = sg + d2s;
}

// ---------------- k1: GH GEMM (gather) + layer1 + u1 matvec ----------------
// GH blocks FIRST (blk 0..127): they carry the HBM-cold strided W_yemb
// gather, so they get CUs earliest. GH at JW=32 (NO=1) halves its
// LDS-issue-bound inner loop. 208 blocks total -> single block-round.
__global__ __launch_bounds__(256) void k1(
    const float* __restrict__ z, const float* __restrict__ Wz1,
    const float* __restrict__ bz1, float* __restrict__ X1,
    const float* __restrict__ Wy2, const float* __restrict__ w_proj,
    float* __restrict__ u1, const float* __restrict__ W_yemb,
    const float* __restrict__ b_yemb, const int* __restrict__ y,
    const float* __restrict__ Wy1, float* __restrict__ GH) {
  int blk = blockIdx.x;
  if (blk < 128)
    gemm_fullk2<1, 0, 32, 0>(blk, nullptr, W_yemb, b_yemb, y, Wy1, nullptr, GH, nullptr);
  else if (blk < 192)
    gemm_fullk2<0, 0, 64, 1>(blk - 128, z, nullptr, nullptr, nullptr, Wz1, bz1, X1, nullptr);
  else
    matvec_block(blk - 192, Wy2, w_proj, u1);
}

// ---------------- k2: layer2 -> zzs (bf16, unscaled) + s finalize ----------
__global__ __launch_bounds__(256) void k2(
    const float* __restrict__ X1, const float* __restrict__ Wz2,
    const float* __restrict__ bz2, unsigned short* __restrict__ zzs,
    const float* __restrict__ GH, const float* __restrict__ u1,
    const float* __restrict__ by1, const float* __restrict__ by2,
    const float* __restrict__ w_proj, float* __restrict__ sv) {
  int blk = blockIdx.x;
  if (blk < 128)
    gemm_fullk2<0, 1, 32, 1>(blk, X1, nullptr, nullptr, nullptr, Wz2, bz2, nullptr, zzs);
  else
    s_block(blk - 128, GH, u1, by1, by2, w_proj, sv);
}

// ---------------- kC: out[b,l] = s[b] * dot(zzs[b,:], W[l,:]) ---------------
// 256 blocks, l-tile 32 (l0 = blk*32), full K=512 — exactly 1 block/CU,
// single scheduling round. zzs is UNSCALED, s[b] applied in epilogue.
// LDS: Bs 32x512 bf16 = 32 KB. XOR-granule swizzle phys = c ^ (row & 7)
// (16-B granules). A-fragments straight from zzs global (64 KB, L2-hot),
// reused for both l-halves (2 accumulators, 32 MFMA/wave).
__global__ __launch_bounds__(256) void kC(const unsigned short* __restrict__ zzs,
                                          const float* __restrict__ W,
                                          const float* __restrict__ sv,
                                          float* __restrict__ out) {
  __shared__ __align__(16) unsigned short Bs[32 * 512];
  __shared__ float ss[64];
  int tid = threadIdx.x;
  int l0 = blockIdx.x * 32;
  if (tid < 64) ss[tid] = sv[tid];
#pragma unroll
  for (int i = 0; i < 8; ++i) {      // 2048 8-float granules of W (32 rows)
    int gi = tid + i * 256, row = gi >> 6, c = gi & 63;
    const float* src = &W[(size_t)(l0 + row) * DD + c * 8];
    float4 v0 = *(const float4*)src;
    float4 v1 = *(const float4*)(src + 4);
    short8 h = {(short)f2bf(v0.x), (short)f2bf(v0.y), (short)f2bf(v0.z),
                (short)f2bf(v0.w), (short)f2bf(v1.x), (short)f2bf(v1.y),
                (short)f2bf(v1.z), (short)f2bf(v1.w)};
    *(short8*)&Bs[row * DD + ((c ^ (row & 7)) << 3)] = h;
  }
  __syncthreads();
  int wave = tid >> 6, lane = tid & 63, quad = lane >> 4, l15 = lane & 15;
  const unsigned short* arow = zzs + (wave * 16 + l15) * DD + quad * 8;
  f32x4 acc0 = {}, acc1 = {};
  short8 apf[4];
#pragma unroll
  for (int p = 0; p < 4; ++p) apf[p] = *(const short8*)(arow + p * 32);
#pragma unroll
  for (int kc = 0; kc < 4; ++kc) {
    short8 cur[4] = {apf[0], apf[1], apf[2], apf[3]};
    if (kc < 3) {
#pragma unroll
      for (int p = 0; p < 4; ++p)
        apf[p] = *(const short8*)(arow + (kc + 1) * 128 + p * 32);
    }
#pragma unroll
    for (int s = 0; s < 4; ++s) {
      int c = kc * 16 + s * 4 + quad;            // k-granule column 0..63
      int sw = (c ^ (l15 & 7)) << 3;             // (l15+16)&7 == l15&7
      short8 b0 = *(const short8*)&Bs[l15 * DD + sw];
      short8 b1 = *(const short8*)&Bs[(l15 + 16) * DD + sw];
      acc0 = __builtin_amdgcn_mfma_f32_16x16x32_bf16(cur[s], b0, acc0, 0, 0, 0);
      acc1 = __builtin_amdgcn_mfma_f32_16x16x32_bf16(cur[s], b1, acc1, 0, 0, 0);
    }
  }
#pragma unroll
  for (int reg = 0; reg < 4; ++reg) {            // b = wave*16 + quad*4 + reg
    int b = wave * 16 + quad * 4 + reg;
    out[(size_t)b * LL + l0 + l15]      = acc0[reg] * ss[b];
    out[(size_t)b * LL + l0 + 16 + l15] = acc1[reg] * ss[b];
  }
}

extern "C" void kernel_launch(void* const* d_in, const int* in_sizes, int n_in,
                              void* d_out, int out_size, void* d_ws, size_t ws_size,
                              hipStream_t stream) {
  const float* z      = (const float*)d_in[0];
  const int*   y      = (const int*)  d_in[1];
  const float* W_yemb = (const float*)d_in[2];
  const float* b_yemb = (const float*)d_in[3];
  const float* Wy1    = (const float*)d_in[4];
  const float* by1    = (const float*)d_in[5];
  const float* Wy2    = (const float*)d_in[6];
  const float* by2    = (const float*)d_in[7];
  const float* Wz1    = (const float*)d_in[8];
  const float* bz1    = (const float*)d_in[9];
  const float* Wz2    = (const float*)d_in[10];
  const float* bz2    = (const float*)d_in[11];
  const float* W_zlat = (const float*)d_in[12];
  const float* w_proj = (const float*)d_in[13];

  float* ws = (float*)d_ws;
  float* X1 = ws;                                  // floats [0     .. 32768)
  float* GH = ws + 32768;                          // floats [32768 .. 65536)
  float* u1 = ws + 65536;                          // [512]
  float* sv = ws + 66048;                          // [64]
  unsigned short* zzs = (unsigned short*)(ws + 66112);   // 32768 shorts (16B-aligned)
  float* out = (float*)d_out;

  k1<<<208, 256, 0, stream>>>(z, Wz1, bz1, X1, Wy2, w_proj, u1, W_yemb, b_yemb, y, Wy1, GH);
  k2<<<144, 256, 0, stream>>>(X1, Wz2, bz2, zzs, GH, u1, by1, by2, w_proj, sv);
  kC<<<256, 256, 0, stream>>>(zzs, W_zlat, sv, out);
}